// Round 1
// baseline (19005.064 us; speedup 1.0000x reference)
//
#include <hip/hip_runtime.h>
#include <hip/hip_bf16.h>

// LSTMOutputProj: 2-layer LSTM (H=1024) over 128 sequential steps, BT=512 rows.
// Persistent cooperative-style kernel, 3 grid-barrier phases per step:
//   A: logits(s-1)+cur(s-1)  B: layer0 cell (MFMA)  C: layer1 cell (MFMA, K=2048)
// Weights pre-transposed to fragment-linearized bf16; c-state in registers.

#define BTROWS 512
#define HD     1024
#define G4     4096
#define NSTEPS 128
#define NOUTC  33

typedef __attribute__((ext_vector_type(8))) short s8v;
typedef __attribute__((ext_vector_type(4))) float f4v;
typedef unsigned int u32;

__device__ __forceinline__ float fsig(float x)  { return 1.0f / (1.0f + __expf(-x)); }
__device__ __forceinline__ float ftanh(float x) { return 2.0f / (1.0f + __expf(-2.0f * x)) - 1.0f; }

__device__ __forceinline__ short f2bf(float x) {
  union { __hip_bfloat16 b; short s; } u; u.b = __float2bfloat16(x); return u.s;
}
__device__ __forceinline__ float bf2f(short s) {
  union { __hip_bfloat16 b; short v; } u; u.v = s; return __bfloat162float(u.b);
}

// ---------------- grid barrier (agent scope, safe across XCD L2s) -------------
__device__ __forceinline__ void gridbar(u32* bar, u32 target) {
  __syncthreads();
  if (threadIdx.x == 0) {
    __threadfence();  // release: write back this XCD's L2
    __hip_atomic_fetch_add(bar, 1u, __ATOMIC_RELAXED, __HIP_MEMORY_SCOPE_AGENT);
    while (__hip_atomic_load(bar, __ATOMIC_RELAXED, __HIP_MEMORY_SCOPE_AGENT) < target) {
      __builtin_amdgcn_s_sleep(1);
    }
    __threadfence();  // acquire: invalidate stale L1/L2 lines
  }
  __syncthreads();
}

// ---------------- precompute: transpose -> fragment-linearized bf16 -----------
// src: fp32 [1024 x 4096] (rows k, cols n). dst tile (ntile,kchunk) is 1KB:
// lane l holds n=16*ntile+(l&15), k=32*kchunk+(l>>4)*8 .. +8  (16B per lane).
__global__ __launch_bounds__(256) void transpose_frag_kernel(
    const float* __restrict__ src, short* __restrict__ dst_hi,
    short* __restrict__ dst_lo, int NK, int koff) {
  __shared__ float St[64][65];
  int n0 = (blockIdx.x & 63) * 64;
  int k0 = (blockIdx.x >> 6) * 64;
  int t = threadIdx.x;
  int nl = t & 63, kl = t >> 6;
#pragma unroll
  for (int it = 0; it < 16; ++it) {
    int k = kl + it * 4;
    St[k][nl] = src[(size_t)(k0 + k) * 4096 + n0 + nl];
  }
  __syncthreads();
  int lane = t & 63, w = t >> 6;
  for (int it = 0; it < 2; ++it) {
    int sub = it * 4 + w;  // 0..7 : 4 ntiles x 2 kchunks
    int nt = sub >> 1, kc = sub & 1;
    int nloc = nt * 16 + (lane & 15);
    int kbase = kc * 32 + (lane >> 4) * 8;
    float v[8];
#pragma unroll
    for (int ii = 0; ii < 8; ++ii) v[ii] = St[kbase + ii][nloc];
    s8v hv;
#pragma unroll
    for (int ii = 0; ii < 8; ++ii) hv[ii] = f2bf(v[ii]);
    size_t ntg = (size_t)(n0 / 16 + nt);
    size_t kcg = (size_t)(k0 / 32 + kc + koff);
    size_t off = (ntg * (size_t)NK + kcg) * 512 + (size_t)lane * 8;
    *(s8v*)(dst_hi + off) = hv;
    if (dst_lo) {
      s8v lv;
#pragma unroll
      for (int ii = 0; ii < 8; ++ii) lv[ii] = f2bf(v[ii] - bf2f(hv[ii]));
      *(s8v*)(dst_lo + off) = lv;
    }
  }
}

// ---------------- precompute: cond = x @ Wc + bc  (fp32, split to bf16 hi/lo) -
__global__ __launch_bounds__(256) void cond_kernel(
    const float* __restrict__ x, const float* __restrict__ Wc,
    const float* __restrict__ bc, short* __restrict__ cond_hi,
    short* __restrict__ cond_lo) {
  __shared__ float xs[8][512];
  int rb = (blockIdx.x >> 2) * 8;
  int cb = (blockIdx.x & 3) * 256;
  int t = threadIdx.x;
  for (int i = t; i < 8 * 512; i += 256)
    xs[i >> 9][i & 511] = x[(size_t)(rb + (i >> 9)) * 512 + (i & 511)];
  __syncthreads();
  float acc[8] = {0, 0, 0, 0, 0, 0, 0, 0};
  for (int k = 0; k < 512; ++k) {
    float w = Wc[(size_t)k * 1024 + cb + t];
#pragma unroll
    for (int rr = 0; rr < 8; ++rr) acc[rr] += xs[rr][k] * w;
  }
  float bcv = bc[cb + t];
#pragma unroll
  for (int rr = 0; rr < 8; ++rr) {
    float v = acc[rr] + bcv;
    short hi = f2bf(v);
    cond_hi[(size_t)(rb + rr) * 1024 + cb + t] = hi;
    cond_lo[(size_t)(rb + rr) * 1024 + cb + t] = f2bf(v - bf2f(hi));
  }
}

// ---------------- precompute: vec0, Wf, b1vec ---------------------------------
// vec0[n] = sum_k bi[k]*Wih0[k][n] + bih0[n] + bhh0[n]
// Wf[n][c] = sum_k Wi[c][k]*Wih0[k][n]   (rank-2 cur path)
__global__ __launch_bounds__(256) void vecs_kernel(
    const float* __restrict__ Wih0, const float* __restrict__ bi,
    const float* __restrict__ Wi, const float* __restrict__ bih0,
    const float* __restrict__ bhh0, const float* __restrict__ bih1,
    const float* __restrict__ bhh1, float* __restrict__ vec0,
    float* __restrict__ Wf, float* __restrict__ b1vec) {
  int n = blockIdx.x * 256 + threadIdx.x;  // 0..4095
  float v0 = 0.f, w0 = 0.f, w1 = 0.f;
  for (int k = 0; k < 1024; ++k) {
    float w = Wih0[(size_t)k * 4096 + n];
    v0 += bi[k] * w;
    w0 += Wi[k] * w;
    w1 += Wi[1024 + k] * w;
  }
  vec0[n] = v0 + bih0[n] + bhh0[n];
  Wf[2 * n + 0] = w0;
  Wf[2 * n + 1] = w1;
  b1vec[n] = bih1[n] + bhh1[n];
}

// ---------------- precompute: WoT[ch][k] = Wo[k][ch] --------------------------
__global__ __launch_bounds__(256) void wot_kernel(const float* __restrict__ Wo,
                                                  float* __restrict__ WoT) {
  int idx = blockIdx.x * 256 + threadIdx.x;
  if (idx >= 33 * 1024) return;
  int ch = idx >> 10, k = idx & 1023;
  WoT[idx] = Wo[(size_t)k * 33 + ch];
}

// ---------------- precompute: const0 = cond @ Wih0[H:] + vec0  (split bf16) ---
__global__ __launch_bounds__(512) void const0_kernel(
    const short* __restrict__ cond_hi, const short* __restrict__ cond_lo,
    const short* __restrict__ WTc_hi, const short* __restrict__ WTc_lo,
    const float* __restrict__ vec0, float* __restrict__ const0) {
  int j = blockIdx.x & 63, i = blockIdx.x >> 6;
  int w = threadIdx.x >> 6, lane = threadIdx.x & 63;
  int quad = lane >> 4, l16 = lane & 15;
  int rowA = i * 128 + w * 16 + l16;
  int rowC = i * 128 + w * 16 + quad * 4;
  int hid = j * 16 + l16;
  const short* ah = cond_hi + (size_t)rowA * 1024 + quad * 8;
  const short* al = cond_lo + (size_t)rowA * 1024 + quad * 8;
  f4v acc[4];
#pragma unroll
  for (int g = 0; g < 4; ++g) acc[g] = (f4v){0.f, 0.f, 0.f, 0.f};
#pragma unroll 2
  for (int kk = 0; kk < 32; ++kk) {
    s8v avh = *(const s8v*)(ah + kk * 32);
    s8v avl = *(const s8v*)(al + kk * 32);
#pragma unroll
    for (int g = 0; g < 4; ++g) {
      size_t off = ((size_t)(g * 64 + j) * 32 + kk) * 512 + (size_t)lane * 8;
      s8v bh = *(const s8v*)(WTc_hi + off);
      s8v bl = *(const s8v*)(WTc_lo + off);
      acc[g] = __builtin_amdgcn_mfma_f32_16x16x32_bf16(avh, bh, acc[g], 0, 0, 0);
      acc[g] = __builtin_amdgcn_mfma_f32_16x16x32_bf16(avh, bl, acc[g], 0, 0, 0);
      acc[g] = __builtin_amdgcn_mfma_f32_16x16x32_bf16(avl, bh, acc[g], 0, 0, 0);
    }
  }
#pragma unroll
  for (int g = 0; g < 4; ++g) {
    float vv = vec0[g * 1024 + hid];
#pragma unroll
    for (int p = 0; p < 4; ++p) {
      int r = rowC + p;
      const0[(size_t)r * G4 + g * 1024 + hid] = acc[g][p] + vv;
    }
  }
}

// ---------------- phase A: logits(sm1) -> out, cur ----------------------------
__device__ void phase_logits(int sm1, int bank, const short* __restrict__ hbuf,
                             const float* __restrict__ WoT,
                             const float* __restrict__ bo,
                             float* __restrict__ out, float* __restrict__ cur,
                             float (*lA)[NOUTC], bool do_cur) {
  int tid = threadIdx.x, bid = blockIdx.x;
  int grp = tid >> 3, l8 = tid & 7;
  for (int q = grp; q < 2 * NOUTC; q += 64) {
    int rloc = (q >= NOUTC) ? 1 : 0;
    int ch = q - rloc * NOUTC;
    int r = 2 * bid + rloc;
    const short* h1 = hbuf + (size_t)r * G4 + bank + 1024;
    const float* wo = WoT + (size_t)ch * 1024;
    float sum = 0.f;
    int k0 = l8 * 128;
#pragma unroll 4
    for (int k = k0; k < k0 + 128; ++k) sum += bf2f(h1[k]) * wo[k];
    sum += __shfl_down(sum, 4, 8);
    sum += __shfl_down(sum, 2, 8);
    sum += __shfl_down(sum, 1, 8);
    if (l8 == 0) {
      float lg = sum + bo[ch];
      lA[rloc][ch] = lg;
      int b = r >> 6, t_ = r & 63;
      out[((size_t)(b * NOUTC + ch) * 64 + t_) * 128 + sm1] = lg;
    }
  }
  __syncthreads();
  if (do_cur && tid < 2) {
    int r = 2 * bid + tid;
    float note = (lA[tid][0] > 0.0f) ? 1.0f : 0.0f;
    float mx = lA[tid][1];
    int mi = 0;
    for (int v = 1; v < 32; ++v)
      if (lA[tid][1 + v] > mx) { mx = lA[tid][1 + v]; mi = v; }
    cur[2 * r + 0] = note;
    cur[2 * r + 1] = (float)mi / 31.0f;
  }
  __syncthreads();
}

// ---------------- main persistent kernel --------------------------------------
__global__ __launch_bounds__(512) void lstm_main(
    const short* __restrict__ WT0, const short* __restrict__ WT1,
    const float* __restrict__ const0, const float* __restrict__ Wf,
    const float* __restrict__ b1vec, const float* __restrict__ WoT,
    const float* __restrict__ bo, const float* __restrict__ sos,
    float* __restrict__ out, short* __restrict__ hbuf,
    float* __restrict__ cur, u32* __restrict__ bar) {
  int bid = blockIdx.x, tid = threadIdx.x;
  int j = bid & 63, i = bid >> 6;
  int w = tid >> 6, lane = tid & 63;
  int quad = lane >> 4, l16 = lane & 15;
  int quad8 = quad * 8;
  __shared__ float lA[2][NOUTC];

  // zero hbuf (both banks): 512*4096 shorts = 262144 uint4; 131072 threads x 2
  {
    uint4 z = {0u, 0u, 0u, 0u};
    uint4* hz = (uint4*)hbuf;
    size_t tg = (size_t)bid * 512 + tid;
    hz[tg * 2 + 0] = z;
    hz[tg * 2 + 1] = z;
  }
  u32 snum = 0;
  ++snum; gridbar(bar, snum * 256u);

  int rowA = i * 128 + w * 16 + l16;      // row for A-operand fragments
  int rowC = i * 128 + w * 16 + quad * 4; // base row for C/D + epilogue
  int hid = j * 16 + l16;

  // step-invariant per-thread loads
  float wfv[4][2], b1v[4], c0v[4][4];
#pragma unroll
  for (int g = 0; g < 4; ++g) {
    wfv[g][0] = Wf[(g * 1024 + hid) * 2 + 0];
    wfv[g][1] = Wf[(g * 1024 + hid) * 2 + 1];
    b1v[g] = b1vec[g * 1024 + hid];
#pragma unroll
    for (int p = 0; p < 4; ++p)
      c0v[g][p] = const0[(size_t)(rowC + p) * G4 + g * 1024 + hid];
  }
  size_t nb0[4], nb1[4];
#pragma unroll
  for (int g = 0; g < 4; ++g) {
    nb0[g] = (size_t)(g * 64 + j) * 32;
    nb1[g] = (size_t)(g * 64 + j) * 64;
  }
  float c0s[4] = {0.f, 0.f, 0.f, 0.f};
  float c1s[4] = {0.f, 0.f, 0.f, 0.f};

  for (int s = 0; s < NSTEPS; ++s) {
    int bank_r = (s & 1) * 2048;
    int bank_w = ((s + 1) & 1) * 2048;

    // ---- Phase A: logits(s-1) + cur(s-1) ----
    if (s == 0) {
      if (tid < 4) {
        int r = 2 * bid + (tid >> 1);
        cur[2 * r + (tid & 1)] = sos[tid & 1];
      }
      __syncthreads();
    } else {
      phase_logits(s - 1, bank_r, hbuf, WoT, bo, out, cur, lA, true);
    }
    ++snum; gridbar(bar, snum * 256u);

    // ---- Phase B: layer 0  g0 = h0_prev @ Whh0 + const0 + cur@Wf ----
    {
      f4v acc[4];
#pragma unroll
      for (int g = 0; g < 4; ++g) acc[g] = (f4v){0.f, 0.f, 0.f, 0.f};
      const short* ap = hbuf + (size_t)rowA * G4 + bank_r + quad8;
#pragma unroll 4
      for (int kk = 0; kk < 32; ++kk) {
        s8v av = *(const s8v*)(ap + kk * 32);
#pragma unroll
        for (int g = 0; g < 4; ++g) {
          s8v bv = *(const s8v*)(WT0 + (nb0[g] + kk) * 512 + (size_t)lane * 8);
          acc[g] = __builtin_amdgcn_mfma_f32_16x16x32_bf16(av, bv, acc[g], 0, 0, 0);
        }
      }
#pragma unroll
      for (int p = 0; p < 4; ++p) {
        int r = rowC + p;
        float cu0 = cur[2 * r + 0], cu1 = cur[2 * r + 1];
        float gi = acc[0][p] + c0v[0][p] + cu0 * wfv[0][0] + cu1 * wfv[0][1];
        float gf = acc[1][p] + c0v[1][p] + cu0 * wfv[1][0] + cu1 * wfv[1][1];
        float gg = acc[2][p] + c0v[2][p] + cu0 * wfv[2][0] + cu1 * wfv[2][1];
        float go = acc[3][p] + c0v[3][p] + cu0 * wfv[3][0] + cu1 * wfv[3][1];
        float cc = fsig(gf) * c0s[p] + fsig(gi) * ftanh(gg);
        c0s[p] = cc;
        hbuf[(size_t)r * G4 + bank_w + hid] = f2bf(fsig(go) * ftanh(cc));
      }
    }
    ++snum; gridbar(bar, snum * 256u);

    // ---- Phase C: layer 1  g1 = h0_new @ Wih1 + h1_prev @ Whh1 + b1 ----
    {
      f4v acc[4];
#pragma unroll
      for (int g = 0; g < 4; ++g) acc[g] = (f4v){0.f, 0.f, 0.f, 0.f};
      const short* ap0 = hbuf + (size_t)rowA * G4 + bank_w + quad8;         // h0 new
      const short* ap1 = hbuf + (size_t)rowA * G4 + bank_r + 1024 + quad8;  // h1 old
#pragma unroll 4
      for (int kk = 0; kk < 32; ++kk) {
        s8v av = *(const s8v*)(ap0 + kk * 32);
#pragma unroll
        for (int g = 0; g < 4; ++g) {
          s8v bv = *(const s8v*)(WT1 + (nb1[g] + kk) * 512 + (size_t)lane * 8);
          acc[g] = __builtin_amdgcn_mfma_f32_16x16x32_bf16(av, bv, acc[g], 0, 0, 0);
        }
      }
#pragma unroll 4
      for (int kk = 0; kk < 32; ++kk) {
        s8v av = *(const s8v*)(ap1 + kk * 32);
#pragma unroll
        for (int g = 0; g < 4; ++g) {
          s8v bv = *(const s8v*)(WT1 + (nb1[g] + 32 + kk) * 512 + (size_t)lane * 8);
          acc[g] = __builtin_amdgcn_mfma_f32_16x16x32_bf16(av, bv, acc[g], 0, 0, 0);
        }
      }
#pragma unroll
      for (int p = 0; p < 4; ++p) {
        int r = rowC + p;
        float gi = acc[0][p] + b1v[0];
        float gf = acc[1][p] + b1v[1];
        float gg = acc[2][p] + b1v[2];
        float go = acc[3][p] + b1v[3];
        float cc = fsig(gf) * c1s[p] + fsig(gi) * ftanh(gg);
        c1s[p] = cc;
        hbuf[(size_t)r * G4 + bank_w + 1024 + hid] = f2bf(fsig(go) * ftanh(cc));
      }
    }
    ++snum; gridbar(bar, snum * 256u);
  }
  // final logits for s=127 (h1(127) sits in bank (128&1)=0)
  phase_logits(NSTEPS - 1, (NSTEPS & 1) * 2048, hbuf, WoT, bo, out, cur, lA, false);
}

// ---------------- host launch -------------------------------------------------
extern "C" void kernel_launch(void* const* d_in, const int* in_sizes, int n_in,
                              void* d_out, int out_size, void* d_ws, size_t ws_size,
                              hipStream_t stream) {
  (void)in_sizes; (void)n_in; (void)out_size; (void)ws_size;
  const float* x    = (const float*)d_in[0];
  const float* sos  = (const float*)d_in[1];
  const float* Wc   = (const float*)d_in[2];
  const float* bc   = (const float*)d_in[3];
  const float* Wi   = (const float*)d_in[4];
  const float* bi   = (const float*)d_in[5];
  const float* Wih0 = (const float*)d_in[6];
  const float* Whh0 = (const float*)d_in[7];
  const float* bih0 = (const float*)d_in[8];
  const float* bhh0 = (const float*)d_in[9];
  const float* Wih1 = (const float*)d_in[10];
  const float* Whh1 = (const float*)d_in[11];
  const float* bih1 = (const float*)d_in[12];
  const float* bhh1 = (const float*)d_in[13];
  const float* Wo   = (const float*)d_in[14];
  const float* bo   = (const float*)d_in[15];
  float* out = (float*)d_out;

  char* p = (char*)d_ws;
  short* WT0    = (short*)p; p += (size_t)256 * 32 * 512 * 2;  // 8 MB
  short* WT1    = (short*)p; p += (size_t)256 * 64 * 512 * 2;  // 16 MB
  short* WTc_hi = (short*)p; p += (size_t)256 * 32 * 512 * 2;  // 8 MB
  short* WTc_lo = (short*)p; p += (size_t)256 * 32 * 512 * 2;  // 8 MB
  float* const0 = (float*)p; p += (size_t)512 * 4096 * 4;      // 8 MB
  short* hbuf   = (short*)p; p += (size_t)512 * 4096 * 2;      // 4 MB
  short* cond_hi= (short*)p; p += (size_t)512 * 1024 * 2;      // 1 MB
  short* cond_lo= (short*)p; p += (size_t)512 * 1024 * 2;      // 1 MB
  float* vec0   = (float*)p; p += 4096 * 4;
  float* Wf     = (float*)p; p += 4096 * 2 * 4;
  float* b1vec  = (float*)p; p += 4096 * 4;
  float* WoT    = (float*)p; p += 33 * 1024 * 4;
  float* cur    = (float*)p; p += 512 * 2 * 4;
  u32*   bar    = (u32*)p;   p += 256;

  hipMemsetAsync(bar, 0, 256, stream);

  transpose_frag_kernel<<<1024, 256, 0, stream>>>(Whh0, WT0, nullptr, 32, 0);
  transpose_frag_kernel<<<1024, 256, 0, stream>>>(Wih1, WT1, nullptr, 64, 0);
  transpose_frag_kernel<<<1024, 256, 0, stream>>>(Whh1, WT1, nullptr, 64, 32);
  transpose_frag_kernel<<<1024, 256, 0, stream>>>(Wih0 + (size_t)1024 * 4096,
                                                  WTc_hi, WTc_lo, 32, 0);
  cond_kernel<<<256, 256, 0, stream>>>(x, Wc, bc, cond_hi, cond_lo);
  vecs_kernel<<<16, 256, 0, stream>>>(Wih0, bi, Wi, bih0, bhh0, bih1, bhh1,
                                      vec0, Wf, b1vec);
  wot_kernel<<<132, 256, 0, stream>>>(Wo, WoT);
  const0_kernel<<<256, 512, 0, stream>>>(cond_hi, cond_lo, WTc_hi, WTc_lo,
                                         vec0, const0);
  lstm_main<<<256, 512, 0, stream>>>(WT0, WT1, const0, Wf, b1vec, WoT, bo, sos,
                                     out, hbuf, cur, bar);
}